// Round 1
// baseline (87268.933 us; speedup 1.0000x reference)
//
#include <hip/hip_runtime.h>
#include <stdint.h>

#define B_    64
#define EMB_  512
#define HID_  1024
#define V_    10000
#define T_    256
#define SOS_  1
#define KC_   128

typedef unsigned long long u64;
typedef unsigned int u32;

__device__ __forceinline__ float sig_(float v) { return 1.0f / (1.0f + __expf(-v)); }

// Stage A[0..63][k0..k0+KC_) into lds, transposed+swizzled:
//   element (k, b) lives at lds[k*64 + (b ^ ((k>>2)&31))]
// Global reads: float4 along k, coalesced. LDS writes: conflict-free via XOR swizzle.
__device__ __forceinline__ void stageA(const float* __restrict__ A, int K, int k0,
                                       float* __restrict__ lds, int tid) {
#pragma unroll
  for (int it = 0; it < 8; ++it) {
    int g   = it * 256 + tid;      // granule 0..2047
    int row = g >> 5;              // batch row (KC_/4 = 32 granules per row)
    int c4  = g & 31;              // float4 index within chunk
    const float4 v = *reinterpret_cast<const float4*>(A + (size_t)row * K + k0 + c4 * 4);
    int swz = row ^ (c4 & 31);
    int kb  = c4 * 4;
    lds[(kb + 0) * 64 + swz] = v.x;
    lds[(kb + 1) * 64 + swz] = v.y;
    lds[(kb + 2) * 64 + swz] = v.z;
    lds[(kb + 3) * 64 + swz] = v.w;
  }
}

__global__ __launch_bounds__(256) void k_init(const float* __restrict__ efs,
                                              const float* __restrict__ embW,
                                              float* __restrict__ h0, float* __restrict__ h1,
                                              float* __restrict__ x) {
  int b = blockIdx.x, tid = threadIdx.x;
  for (int k = tid; k < HID_; k += 256) {
    h0[(size_t)b * HID_ + k] = efs[(size_t)b * HID_ + k];
    h1[(size_t)b * HID_ + k] = efs[(size_t)B_ * HID_ + (size_t)b * HID_ + k];
  }
  for (int k = tid; k < EMB_; k += 256) {
    float v = embW[(size_t)SOS_ * EMB_ + k];
    x[(size_t)b * EMB_ + k] = v > 0.f ? v : 0.f;
  }
}

// Phase 1: gi0 = x@Wih0^T, gh0 = h0@Whh0^T  -> fused GRU0 combine -> h0n   (WGs 0..127)
//          gh1 = h1@Whh1^T + bhh1                                          (WGs 128..255)
__global__ __launch_bounds__(256) void k_phase1(
    const float* __restrict__ x, const float* __restrict__ h0, const float* __restrict__ h1,
    const float* __restrict__ Wih0, const float* __restrict__ Whh0,
    const float* __restrict__ bih0, const float* __restrict__ bhh0,
    const float* __restrict__ Whh1, const float* __restrict__ bhh1,
    float* __restrict__ h0n, float* __restrict__ gh1) {
  __shared__ float ldsH[KC_ * 64];
  __shared__ float ldsX[KC_ * 64];
  const int tid = threadIdx.x;
  const int b   = tid & 63;
  const int tc  = tid >> 6;
  const int wg  = blockIdx.x;

  if (wg < 128) {
    // type A: 8 columns per WG, 2 per wave. Each wave owns cols {c0, c0+1} of all 3 gates.
    const int c0 = __builtin_amdgcn_readfirstlane(wg * 8 + tc * 2);
    float acc[12];
#pragma unroll
    for (int i = 0; i < 12; ++i) acc[i] = 0.f;
    const float* wi[6];
    const float* wh[6];
#pragma unroll
    for (int cc = 0; cc < 2; ++cc)
#pragma unroll
      for (int g3 = 0; g3 < 3; ++g3) {
        wi[cc * 3 + g3] = Wih0 + (size_t)(g3 * HID_ + c0 + cc) * EMB_;
        wh[cc * 3 + g3] = Whh0 + (size_t)(g3 * HID_ + c0 + cc) * HID_;
      }
    for (int k0 = 0; k0 < HID_; k0 += KC_) {
      stageA(h0, HID_, k0, ldsH, tid);
      if (k0 < EMB_) stageA(x, EMB_, k0, ldsX, tid);
      __syncthreads();
      if (k0 < EMB_) {
#pragma unroll 4
        for (int g = 0; g < KC_ / 4; ++g) {
          const int bs = b ^ (g & 31);
#pragma unroll
          for (int u = 0; u < 4; ++u) {
            const int k  = g * 4 + u;
            const float ah = ldsH[k * 64 + bs];
            const float ax = ldsX[k * 64 + bs];
#pragma unroll
            for (int j = 0; j < 6; ++j) acc[j] = fmaf(ax, wi[j][k0 + k], acc[j]);
#pragma unroll
            for (int j = 0; j < 6; ++j) acc[6 + j] = fmaf(ah, wh[j][k0 + k], acc[6 + j]);
          }
        }
      } else {
#pragma unroll 4
        for (int g = 0; g < KC_ / 4; ++g) {
          const int bs = b ^ (g & 31);
#pragma unroll
          for (int u = 0; u < 4; ++u) {
            const int k  = g * 4 + u;
            const float ah = ldsH[k * 64 + bs];
#pragma unroll
            for (int j = 0; j < 6; ++j) acc[6 + j] = fmaf(ah, wh[j][k0 + k], acc[6 + j]);
          }
        }
      }
      __syncthreads();
    }
    // fused GRU0 combine for this wave's two columns
#pragma unroll
    for (int cc = 0; cc < 2; ++cc) {
      const int c = c0 + cc;
      float ir = acc[cc * 3 + 0] + bih0[c];
      float iz = acc[cc * 3 + 1] + bih0[HID_ + c];
      float in = acc[cc * 3 + 2] + bih0[2 * HID_ + c];
      float hr = acc[6 + cc * 3 + 0] + bhh0[c];
      float hz = acc[6 + cc * 3 + 1] + bhh0[HID_ + c];
      float hn = acc[6 + cc * 3 + 2] + bhh0[2 * HID_ + c];
      float r = sig_(ir + hr), z = sig_(iz + hz);
      float n = tanhf(in + r * hn);
      float hv = h0[(size_t)b * HID_ + c];
      h0n[(size_t)b * HID_ + c] = (1.f - z) * n + z * hv;
    }
  } else {
    // type B: gh1 = h1 @ Whh1^T + bhh1, 24 columns per WG, 6 per wave
    const int wg2 = wg - 128;
    const int c0  = __builtin_amdgcn_readfirstlane(wg2 * 24 + tc * 6);
    float acc[6];
#pragma unroll
    for (int i = 0; i < 6; ++i) acc[i] = 0.f;
    const float* wr[6];
#pragma unroll
    for (int j = 0; j < 6; ++j) wr[j] = Whh1 + (size_t)(c0 + j) * HID_;
    for (int k0 = 0; k0 < HID_; k0 += KC_) {
      stageA(h1, HID_, k0, ldsH, tid);
      __syncthreads();
#pragma unroll 4
      for (int g = 0; g < KC_ / 4; ++g) {
        const int bs = b ^ (g & 31);
#pragma unroll
        for (int u = 0; u < 4; ++u) {
          const int k  = g * 4 + u;
          const float ah = ldsH[k * 64 + bs];
#pragma unroll
          for (int j = 0; j < 6; ++j) acc[j] = fmaf(ah, wr[j][k0 + k], acc[j]);
        }
      }
      __syncthreads();
    }
#pragma unroll
    for (int j = 0; j < 6; ++j)
      gh1[(size_t)b * (3 * HID_) + c0 + j] = acc[j] + bhh1[c0 + j];
  }
}

// Phase 2: gi1 = h0n@Wih1^T -> fused GRU1 combine with gh1 -> h1n. One column per thread.
__global__ __launch_bounds__(256) void k_phase2(
    const float* __restrict__ h0n, const float* __restrict__ gh1, const float* __restrict__ h1,
    const float* __restrict__ Wih1, const float* __restrict__ bih1, float* __restrict__ h1n) {
  __shared__ float ldsA[KC_ * 64];
  const int tid = threadIdx.x;
  const int b   = tid & 63;
  const int tc  = tid >> 6;
  const int c   = __builtin_amdgcn_readfirstlane((int)blockIdx.x * 4 + tc);
  float a0 = 0.f, a1 = 0.f, a2 = 0.f;
  const float* w0 = Wih1 + (size_t)c * HID_;
  const float* w1 = Wih1 + (size_t)(HID_ + c) * HID_;
  const float* w2 = Wih1 + (size_t)(2 * HID_ + c) * HID_;
  for (int k0 = 0; k0 < HID_; k0 += KC_) {
    stageA(h0n, HID_, k0, ldsA, tid);
    __syncthreads();
#pragma unroll 4
    for (int g = 0; g < KC_ / 4; ++g) {
      const int bs = b ^ (g & 31);
#pragma unroll
      for (int u = 0; u < 4; ++u) {
        const int k = g * 4 + u;
        const float a = ldsA[k * 64 + bs];
        a0 = fmaf(a, w0[k0 + k], a0);
        a1 = fmaf(a, w1[k0 + k], a1);
        a2 = fmaf(a, w2[k0 + k], a2);
      }
    }
    __syncthreads();
  }
  float ir = a0 + bih1[c], iz = a1 + bih1[HID_ + c], in = a2 + bih1[2 * HID_ + c];
  float hr = gh1[(size_t)b * (3 * HID_) + c];
  float hz = gh1[(size_t)b * (3 * HID_) + HID_ + c];
  float hn = gh1[(size_t)b * (3 * HID_) + 2 * HID_ + c];
  float r = sig_(ir + hr), z = sig_(iz + hz);
  float n = tanhf(in + r * hn);
  float hv = h1[(size_t)b * HID_ + c];
  h1n[(size_t)b * HID_ + c] = (1.f - z) * n + z * hv;
}

// Phase 3: hid = relu(h1n @ pW1^T + pb1). One column per thread.
__global__ __launch_bounds__(256) void k_phase3(
    const float* __restrict__ h1n, const float* __restrict__ pW1,
    const float* __restrict__ pb1, float* __restrict__ hid) {
  __shared__ float ldsA[KC_ * 64];
  const int tid = threadIdx.x;
  const int b   = tid & 63;
  const int tc  = tid >> 6;
  const int c   = __builtin_amdgcn_readfirstlane((int)blockIdx.x * 4 + tc);
  float a0 = 0.f;
  const float* w0 = pW1 + (size_t)c * HID_;
  for (int k0 = 0; k0 < HID_; k0 += KC_) {
    stageA(h1n, HID_, k0, ldsA, tid);
    __syncthreads();
#pragma unroll 4
    for (int g = 0; g < KC_ / 4; ++g) {
      const int bs = b ^ (g & 31);
#pragma unroll
      for (int u = 0; u < 4; ++u) {
        const int k = g * 4 + u;
        a0 = fmaf(ldsA[k * 64 + bs], w0[k0 + k], a0);
      }
    }
    __syncthreads();
  }
  float v = a0 + pb1[c];
  hid[(size_t)b * HID_ + c] = v > 0.f ? v : 0.f;
}

// Phase 4: logits tile (64 x 40) = hid @ pW2^T + pb2; write to out; per-WG argmax partials.
__global__ __launch_bounds__(256) void k_phase4(
    const float* __restrict__ hid, const float* __restrict__ pW2,
    const float* __restrict__ pb2, float* __restrict__ out,
    u64* __restrict__ part, int t) {
  __shared__ float ldsA[KC_ * 64];
  __shared__ float ldsO[64 * 41];
  const int tid = threadIdx.x;
  const int b   = tid & 63;
  const int tc  = tid >> 6;
  const int wg  = blockIdx.x;
  const int c0  = wg * 40;
  float acc[10];
#pragma unroll
  for (int i = 0; i < 10; ++i) acc[i] = 0.f;
  const float* wr[10];
  const int cbase = __builtin_amdgcn_readfirstlane(c0 + tc * 10);
#pragma unroll
  for (int j = 0; j < 10; ++j) wr[j] = pW2 + (size_t)(cbase + j) * HID_;
  for (int k0 = 0; k0 < HID_; k0 += KC_) {
    stageA(hid, HID_, k0, ldsA, tid);
    __syncthreads();
#pragma unroll 2
    for (int g = 0; g < KC_ / 4; ++g) {
      const int bs = b ^ (g & 31);
#pragma unroll
      for (int u = 0; u < 4; ++u) {
        const int k = g * 4 + u;
        const float a = ldsA[k * 64 + bs];
#pragma unroll
        for (int j = 0; j < 10; ++j) acc[j] = fmaf(a, wr[j][k0 + k], acc[j]);
      }
    }
    __syncthreads();
  }
#pragma unroll
  for (int j = 0; j < 10; ++j) ldsO[b * 41 + tc * 10 + j] = acc[j] + pb2[cbase + j];
  __syncthreads();
  // coalesced logits store: out[b][t][v]
  for (int i = tid; i < 64 * 40; i += 256) {
    int bb = i / 40;
    int cc = i - bb * 40;
    out[((size_t)bb * T_ + t) * V_ + c0 + cc] = ldsO[bb * 41 + cc];
  }
  // per-batch partial argmax over this WG's 40 columns (first-index tie-break)
  if (tid < 64) {
    float best = -3.4e38f;
    int bi = 0;
    for (int cc = 0; cc < 40; ++cc) {
      float v = ldsO[tid * 41 + cc];
      if (v > best) { best = v; bi = cc; }
    }
    u32 kb = __float_as_uint(best);
    kb = (kb & 0x80000000u) ? ~kb : (kb | 0x80000000u);
    u64 pk = ((u64)kb << 32) | (u64)(0xFFFFFFFFu - (u32)(c0 + bi));
    part[(size_t)tid * 256 + wg] = pk;
  }
}

// Phase 5: final argmax reduce (250 partials per batch) + embedding lookup + relu -> x
__global__ __launch_bounds__(256) void k_phase5(const u64* __restrict__ part,
                                                const float* __restrict__ embW,
                                                float* __restrict__ x) {
  __shared__ u64 red[256];
  const int b = blockIdx.x, tid = threadIdx.x;
  u64 k = (tid < 250) ? part[(size_t)b * 256 + tid] : 0ull;
  red[tid] = k;
  __syncthreads();
  for (int s = 128; s > 0; s >>= 1) {
    if (tid < s) {
      u64 o = red[tid + s];
      if (o > red[tid]) red[tid] = o;
    }
    __syncthreads();
  }
  const int tok = (int)(0xFFFFFFFFu - (u32)(red[0] & 0xFFFFFFFFu));
  const float2* src = reinterpret_cast<const float2*>(embW + (size_t)tok * EMB_);
  float2* dst = reinterpret_cast<float2*>(x + (size_t)b * EMB_);
  float2 v = src[tid];
  v.x = v.x > 0.f ? v.x : 0.f;
  v.y = v.y > 0.f ? v.y : 0.f;
  dst[tid] = v;
}

extern "C" void kernel_launch(void* const* d_in, const int* in_sizes, int n_in,
                              void* d_out, int out_size, void* d_ws, size_t ws_size,
                              hipStream_t stream) {
  (void)in_sizes; (void)n_in; (void)out_size; (void)ws_size;
  const float* efs  = (const float*)d_in[1];
  const float* embW = (const float*)d_in[2];
  const float* Wih0 = (const float*)d_in[3];
  const float* Whh0 = (const float*)d_in[4];
  const float* bih0 = (const float*)d_in[5];
  const float* bhh0 = (const float*)d_in[6];
  const float* Wih1 = (const float*)d_in[7];
  const float* Whh1 = (const float*)d_in[8];
  const float* bih1 = (const float*)d_in[9];
  const float* bhh1 = (const float*)d_in[10];
  const float* pW1  = (const float*)d_in[11];
  const float* pb1  = (const float*)d_in[12];
  const float* pW2  = (const float*)d_in[13];
  const float* pb2  = (const float*)d_in[14];
  float* out = (float*)d_out;

  float* ws  = (float*)d_ws;
  float* h0a = ws;
  float* h0b = h0a + 65536;
  float* h1a = h0b + 65536;
  float* h1b = h1a + 65536;
  float* x   = h1b + 65536;            // 64*512
  float* gh1 = x + 32768;              // 64*3072
  float* hid = gh1 + 196608;           // 64*1024
  u64*  part = (u64*)(hid + 65536);    // 64*256 u64

  k_init<<<dim3(B_), dim3(256), 0, stream>>>(efs, embW, h0a, h1a, x);
  for (int t = 0; t < T_; ++t) {
    float* hc0 = (t & 1) ? h0b : h0a;
    float* hn0 = (t & 1) ? h0a : h0b;
    float* hc1 = (t & 1) ? h1b : h1a;
    float* hn1 = (t & 1) ? h1a : h1b;
    k_phase1<<<dim3(256), dim3(256), 0, stream>>>(x, hc0, hc1, Wih0, Whh0, bih0, bhh0,
                                                  Whh1, bhh1, hn0, gh1);
    k_phase2<<<dim3(256), dim3(256), 0, stream>>>(hn0, gh1, hc1, Wih1, bih1, hn1);
    k_phase3<<<dim3(256), dim3(256), 0, stream>>>(hn1, pW1, pb1, hid);
    k_phase4<<<dim3(250), dim3(256), 0, stream>>>(hid, pW2, pb2, out, part, t);
    if (t + 1 < T_) k_phase5<<<dim3(B_), dim3(256), 0, stream>>>(part, embW, x);
  }
}

// Round 2
// 55916.559 us; speedup vs baseline: 1.5607x; 1.5607x over previous
//
#include <hip/hip_runtime.h>
#include <stdint.h>

#define B_    64
#define EMB_  512
#define HID_  1024
#define V_    10000
#define T_    256
#define SOS_  1

typedef unsigned long long u64;
typedef unsigned int u32;

__device__ __forceinline__ float sig_(float v) { return 1.0f / (1.0f + __expf(-v)); }

// Stage a [64][K] row-major global chunk (cols k0..k0+127) into swizzled LDS.
// LDS layout (float4 units): lds4[b*32 + (c4 ^ (b&31))]  -- conflict-free store & b128 read.
__device__ __forceinline__ void stage_bk(const float* __restrict__ A, int K, int k0,
                                         float4* __restrict__ lds4, int tid) {
#pragma unroll
  for (int it = 0; it < 8; ++it) {
    int f  = it * 256 + tid;
    int bb = f >> 5;
    int c4 = f & 31;
    float4 v = *reinterpret_cast<const float4*>(A + (size_t)bb * K + k0 + c4 * 4);
    lds4[bb * 32 + (c4 ^ (bb & 31))] = v;
  }
}

// Same, but gathering rows from emb[tok[b]] with fused ReLU (for the x stream).
__device__ __forceinline__ void stage_emb(const float* __restrict__ embW,
                                          const int* __restrict__ tokL, int k0,
                                          float4* __restrict__ lds4, int tid) {
#pragma unroll
  for (int it = 0; it < 8; ++it) {
    int f  = it * 256 + tid;
    int bb = f >> 5;
    int c4 = f & 31;
    float4 v = *reinterpret_cast<const float4*>(embW + (size_t)tokL[bb] * EMB_ + k0 + c4 * 4);
    v.x = v.x > 0.f ? v.x : 0.f;
    v.y = v.y > 0.f ? v.y : 0.f;
    v.z = v.z > 0.f ? v.z : 0.f;
    v.w = v.w > 0.f ? v.w : 0.f;
    lds4[bb * 32 + (c4 ^ (bb & 31))] = v;
  }
}

__global__ __launch_bounds__(256) void k_init(const float* __restrict__ efs,
                                              float* __restrict__ h0, float* __restrict__ h1,
                                              u64* __restrict__ part) {
  int b = blockIdx.x, tid = threadIdx.x;
  for (int k = tid; k < HID_; k += 256) {
    h0[(size_t)b * HID_ + k] = efs[(size_t)b * HID_ + k];
    h1[(size_t)b * HID_ + k] = efs[(size_t)B_ * HID_ + (size_t)b * HID_ + k];
  }
  if (tid == 0) part[b] = (u64)(0xFFFFFFFFu - (u32)SOS_);  // token = SOS
}

// Phase 1:
//  WGs 0..255   (type A): GRU0. wave = 1 column c; thread: 6 accum (3 gi over x, 3 gh over h0) -> h0n
//  WGs 256..511 (type B): gh1 = h1 @ Whh1^T + bhh1 (3 gates of col c per wave) -> gh1T[g*H+c][b]
__global__ __launch_bounds__(256, 2) void k_phase1(
    const u64* __restrict__ part, const float* __restrict__ embW,
    const float* __restrict__ h0, const float* __restrict__ h1,
    const float* __restrict__ Wih0, const float* __restrict__ Whh0,
    const float* __restrict__ bih0, const float* __restrict__ bhh0,
    const float* __restrict__ Whh1, const float* __restrict__ bhh1,
    float* __restrict__ h0n, float* __restrict__ gh1T) {
  __shared__ __align__(16) float ldsH[64 * 128];
  __shared__ __align__(16) float ldsX[64 * 128];
  __shared__ int tokL[64];
  float4* ldsH4 = reinterpret_cast<float4*>(ldsH);
  float4* ldsX4 = reinterpret_cast<float4*>(ldsX);
  const int tid = threadIdx.x;
  const int b   = tid & 63;
  const int bx  = b & 31;
  const int tc  = tid >> 6;
  const int wg  = blockIdx.x;

  if (wg < 256) {
    if (tid < 64) tokL[tid] = (int)(0xFFFFFFFFu - (u32)(part[tid] & 0xFFFFFFFFu));
    __syncthreads();
    const int c = __builtin_amdgcn_readfirstlane(wg * 4 + tc);
    float ai0 = 0.f, ai1 = 0.f, ai2 = 0.f, ah0 = 0.f, ah1 = 0.f, ah2 = 0.f;
    const float* wi0 = Wih0 + (size_t)c * EMB_;
    const float* wi1 = Wih0 + (size_t)(HID_ + c) * EMB_;
    const float* wi2 = Wih0 + (size_t)(2 * HID_ + c) * EMB_;
    const float* wh0 = Whh0 + (size_t)c * HID_;
    const float* wh1 = Whh0 + (size_t)(HID_ + c) * HID_;
    const float* wh2 = Whh0 + (size_t)(2 * HID_ + c) * HID_;
    for (int k0 = 0; k0 < HID_; k0 += 128) {
      stage_bk(h0, HID_, k0, ldsH4, tid);
      if (k0 < EMB_) stage_emb(embW, tokL, k0, ldsX4, tid);
      __syncthreads();
      if (k0 < EMB_) {
#pragma unroll 4
        for (int k4 = 0; k4 < 32; ++k4) {
          const float4 hv = ldsH4[b * 32 + (k4 ^ bx)];
          const float4 xv = ldsX4[b * 32 + (k4 ^ bx)];
          const int kk = k0 + k4 * 4;
#pragma unroll
          for (int u = 0; u < 4; ++u) {
            const float hh = (&hv.x)[u];
            const float xx = (&xv.x)[u];
            ai0 = fmaf(xx, wi0[kk + u], ai0);
            ai1 = fmaf(xx, wi1[kk + u], ai1);
            ai2 = fmaf(xx, wi2[kk + u], ai2);
            ah0 = fmaf(hh, wh0[kk + u], ah0);
            ah1 = fmaf(hh, wh1[kk + u], ah1);
            ah2 = fmaf(hh, wh2[kk + u], ah2);
          }
        }
      } else {
#pragma unroll 4
        for (int k4 = 0; k4 < 32; ++k4) {
          const float4 hv = ldsH4[b * 32 + (k4 ^ bx)];
          const int kk = k0 + k4 * 4;
#pragma unroll
          for (int u = 0; u < 4; ++u) {
            const float hh = (&hv.x)[u];
            ah0 = fmaf(hh, wh0[kk + u], ah0);
            ah1 = fmaf(hh, wh1[kk + u], ah1);
            ah2 = fmaf(hh, wh2[kk + u], ah2);
          }
        }
      }
      __syncthreads();
    }
    const float ir = ai0 + bih0[c], iz = ai1 + bih0[HID_ + c], in = ai2 + bih0[2 * HID_ + c];
    const float hr = ah0 + bhh0[c], hz = ah1 + bhh0[HID_ + c], hn = ah2 + bhh0[2 * HID_ + c];
    const float r = sig_(ir + hr), z = sig_(iz + hz);
    const float n = tanhf(in + r * hn);
    const float hv = h0[(size_t)b * HID_ + c];
    h0n[(size_t)b * HID_ + c] = (1.f - z) * n + z * hv;
  } else {
    const int c = __builtin_amdgcn_readfirstlane((wg - 256) * 4 + tc);
    float a0 = 0.f, a1 = 0.f, a2 = 0.f;
    const float* w0 = Whh1 + (size_t)c * HID_;
    const float* w1 = Whh1 + (size_t)(HID_ + c) * HID_;
    const float* w2 = Whh1 + (size_t)(2 * HID_ + c) * HID_;
    for (int k0 = 0; k0 < HID_; k0 += 128) {
      stage_bk(h1, HID_, k0, ldsH4, tid);
      __syncthreads();
#pragma unroll 4
      for (int k4 = 0; k4 < 32; ++k4) {
        const float4 hv = ldsH4[b * 32 + (k4 ^ bx)];
        const int kk = k0 + k4 * 4;
#pragma unroll
        for (int u = 0; u < 4; ++u) {
          const float hh = (&hv.x)[u];
          a0 = fmaf(hh, w0[kk + u], a0);
          a1 = fmaf(hh, w1[kk + u], a1);
          a2 = fmaf(hh, w2[kk + u], a2);
        }
      }
      __syncthreads();
    }
    gh1T[(size_t)(0 * HID_ + c) * 64 + b] = a0 + bhh1[c];
    gh1T[(size_t)(1 * HID_ + c) * 64 + b] = a1 + bhh1[HID_ + c];
    gh1T[(size_t)(2 * HID_ + c) * 64 + b] = a2 + bhh1[2 * HID_ + c];
  }
}

// Phase 2: gi1 = h0n @ Wih1^T ; combine with gh1T -> h1n. wave = 1 col, 3 accum.
__global__ __launch_bounds__(256, 2) void k_phase2(
    const float* __restrict__ h0n, const float* __restrict__ gh1T, const float* __restrict__ h1,
    const float* __restrict__ Wih1, const float* __restrict__ bih1, float* __restrict__ h1n) {
  __shared__ __align__(16) float ldsA[64 * 128];
  float4* lds4 = reinterpret_cast<float4*>(ldsA);
  const int tid = threadIdx.x;
  const int b   = tid & 63;
  const int bx  = b & 31;
  const int tc  = tid >> 6;
  const int c   = __builtin_amdgcn_readfirstlane((int)blockIdx.x * 4 + tc);
  float a0 = 0.f, a1 = 0.f, a2 = 0.f;
  const float* w0 = Wih1 + (size_t)c * HID_;
  const float* w1 = Wih1 + (size_t)(HID_ + c) * HID_;
  const float* w2 = Wih1 + (size_t)(2 * HID_ + c) * HID_;
  for (int k0 = 0; k0 < HID_; k0 += 128) {
    stage_bk(h0n, HID_, k0, lds4, tid);
    __syncthreads();
#pragma unroll 4
    for (int k4 = 0; k4 < 32; ++k4) {
      const float4 av = lds4[b * 32 + (k4 ^ bx)];
      const int kk = k0 + k4 * 4;
#pragma unroll
      for (int u = 0; u < 4; ++u) {
        const float aa = (&av.x)[u];
        a0 = fmaf(aa, w0[kk + u], a0);
        a1 = fmaf(aa, w1[kk + u], a1);
        a2 = fmaf(aa, w2[kk + u], a2);
      }
    }
    __syncthreads();
  }
  const float ir = a0 + bih1[c], iz = a1 + bih1[HID_ + c], in = a2 + bih1[2 * HID_ + c];
  const float hr = gh1T[(size_t)(0 * HID_ + c) * 64 + b];
  const float hz = gh1T[(size_t)(1 * HID_ + c) * 64 + b];
  const float hn = gh1T[(size_t)(2 * HID_ + c) * 64 + b];
  const float r = sig_(ir + hr), z = sig_(iz + hz);
  const float n = tanhf(in + r * hn);
  const float hv = h1[(size_t)b * HID_ + c];
  h1n[(size_t)b * HID_ + c] = (1.f - z) * n + z * hv;
}

// Phase 3: hid = relu(h1n @ pW1^T + pb1). wave = 2 cols. Also resets argmax accumulator.
__global__ __launch_bounds__(256, 2) void k_phase3(
    const float* __restrict__ h1n, const float* __restrict__ pW1,
    const float* __restrict__ pb1, float* __restrict__ hid, u64* __restrict__ part) {
  __shared__ __align__(16) float ldsA[64 * 128];
  float4* lds4 = reinterpret_cast<float4*>(ldsA);
  const int tid = threadIdx.x;
  const int b   = tid & 63;
  const int bx  = b & 31;
  const int tc  = tid >> 6;
  const int c0  = __builtin_amdgcn_readfirstlane((int)blockIdx.x * 8 + tc * 2);
  if (blockIdx.x == 0 && tid < 64) part[tid] = 0ull;
  float a0 = 0.f, a1 = 0.f;
  const float* w0 = pW1 + (size_t)c0 * HID_;
  const float* w1 = pW1 + (size_t)(c0 + 1) * HID_;
  for (int k0 = 0; k0 < HID_; k0 += 128) {
    stage_bk(h1n, HID_, k0, lds4, tid);
    __syncthreads();
#pragma unroll 4
    for (int k4 = 0; k4 < 32; ++k4) {
      const float4 av = lds4[b * 32 + (k4 ^ bx)];
      const int kk = k0 + k4 * 4;
#pragma unroll
      for (int u = 0; u < 4; ++u) {
        const float aa = (&av.x)[u];
        a0 = fmaf(aa, w0[kk + u], a0);
        a1 = fmaf(aa, w1[kk + u], a1);
      }
    }
    __syncthreads();
  }
  const float v0 = a0 + pb1[c0];
  const float v1 = a1 + pb1[c0 + 1];
  hid[(size_t)b * HID_ + c0]     = v0 > 0.f ? v0 : 0.f;
  hid[(size_t)b * HID_ + c0 + 1] = v1 > 0.f ? v1 : 0.f;
}

// Phase 4: logits tile (64 x 20) = hid @ pW2^T + pb2; write out; argmax via packed atomicMax.
__global__ __launch_bounds__(256, 2) void k_phase4(
    const float* __restrict__ hid, const float* __restrict__ pW2,
    const float* __restrict__ pb2, float* __restrict__ out,
    u64* __restrict__ part, int t) {
  __shared__ __align__(16) float ldsA[64 * 128];
  __shared__ float ldsO[64 * 21];
  float4* lds4 = reinterpret_cast<float4*>(ldsA);
  const int tid = threadIdx.x;
  const int b   = tid & 63;
  const int bx  = b & 31;
  const int tc  = tid >> 6;
  const int wg  = blockIdx.x;
  const int cb  = __builtin_amdgcn_readfirstlane(wg * 20 + tc * 5);
  float acc[5];
#pragma unroll
  for (int i = 0; i < 5; ++i) acc[i] = 0.f;
  const float* wr[5];
#pragma unroll
  for (int j = 0; j < 5; ++j) wr[j] = pW2 + (size_t)(cb + j) * HID_;
  for (int k0 = 0; k0 < HID_; k0 += 128) {
    stage_bk(hid, HID_, k0, lds4, tid);
    __syncthreads();
#pragma unroll 4
    for (int k4 = 0; k4 < 32; ++k4) {
      const float4 av = lds4[b * 32 + (k4 ^ bx)];
      const int kk = k0 + k4 * 4;
#pragma unroll
      for (int u = 0; u < 4; ++u) {
        const float aa = (&av.x)[u];
#pragma unroll
        for (int j = 0; j < 5; ++j) acc[j] = fmaf(aa, wr[j][kk + u], acc[j]);
      }
    }
    __syncthreads();
  }
#pragma unroll
  for (int j = 0; j < 5; ++j) ldsO[b * 21 + tc * 5 + j] = acc[j] + pb2[cb + j];
  __syncthreads();
  const int c0 = wg * 20;
  for (int i = tid; i < 64 * 20; i += 256) {
    int bb = i / 20;
    int cc = i - bb * 20;
    out[((size_t)bb * T_ + t) * V_ + c0 + cc] = ldsO[bb * 21 + cc];
  }
  if (tid < 64) {
    float best = -3.4e38f;
    int bi = 0;
#pragma unroll
    for (int cc = 0; cc < 20; ++cc) {
      float v = ldsO[tid * 21 + cc];
      if (v > best) { best = v; bi = cc; }
    }
    u32 kb = __float_as_uint(best);
    kb = (kb & 0x80000000u) ? ~kb : (kb | 0x80000000u);
    u64 pk = ((u64)kb << 32) | (u64)(0xFFFFFFFFu - (u32)(c0 + bi));
    atomicMax(&part[tid], pk);
  }
}

extern "C" void kernel_launch(void* const* d_in, const int* in_sizes, int n_in,
                              void* d_out, int out_size, void* d_ws, size_t ws_size,
                              hipStream_t stream) {
  (void)in_sizes; (void)n_in; (void)out_size; (void)ws_size;
  const float* efs  = (const float*)d_in[1];
  const float* embW = (const float*)d_in[2];
  const float* Wih0 = (const float*)d_in[3];
  const float* Whh0 = (const float*)d_in[4];
  const float* bih0 = (const float*)d_in[5];
  const float* bhh0 = (const float*)d_in[6];
  const float* Wih1 = (const float*)d_in[7];
  const float* Whh1 = (const float*)d_in[8];
  const float* bih1 = (const float*)d_in[9];
  const float* bhh1 = (const float*)d_in[10];
  const float* pW1  = (const float*)d_in[11];
  const float* pb1  = (const float*)d_in[12];
  const float* pW2  = (const float*)d_in[13];
  const float* pb2  = (const float*)d_in[14];
  float* out = (float*)d_out;

  float* ws   = (float*)d_ws;
  float* h0a  = ws;                 // 64*1024
  float* h0b  = h0a + 65536;
  float* h1a  = h0b + 65536;
  float* h1b  = h1a + 65536;
  float* gh1T = h1b + 65536;        // 3*1024*64
  float* hid  = gh1T + 196608;      // 64*1024
  u64*   part = (u64*)(hid + 65536);// 64

  k_init<<<dim3(B_), dim3(256), 0, stream>>>(efs, h0a, h1a, part);
  for (int t = 0; t < T_; ++t) {
    float* hc0 = (t & 1) ? h0b : h0a;
    float* hn0 = (t & 1) ? h0a : h0b;
    float* hc1 = (t & 1) ? h1b : h1a;
    float* hn1 = (t & 1) ? h1a : h1b;
    k_phase1<<<dim3(512), dim3(256), 0, stream>>>(part, embW, hc0, hc1, Wih0, Whh0,
                                                  bih0, bhh0, Whh1, bhh1, hn0, gh1T);
    k_phase2<<<dim3(256), dim3(256), 0, stream>>>(hn0, gh1T, hc1, Wih1, bih1, hn1);
    k_phase3<<<dim3(128), dim3(256), 0, stream>>>(hn1, pW1, pb1, hid, part);
    k_phase4<<<dim3(500), dim3(256), 0, stream>>>(hid, pW2, pb2, out, part, t);
  }
}

// Round 3
// 49422.208 us; speedup vs baseline: 1.7658x; 1.1314x over previous
//
#include <hip/hip_runtime.h>
#include <stdint.h>

#define B_    64
#define EMB_  512
#define HID_  1024
#define V_    10000
#define T_    256
#define SOS_  1

typedef unsigned long long u64;
typedef unsigned int u32;

__device__ __forceinline__ float sig_(float v) { return 1.0f / (1.0f + __expf(-v)); }

// ---- LDS chunk geometry ----
// Two k-split buffers (s=0,1), each [i4:16][lane:64] float4, XOR-swizzled:
//   float4 slot = s*1024 + i4*64 + h*32 + (r ^ i4)   (r = b_local 0..31, h = k-half)
// Consumer lane l (h = l>>5, r = l&31): vbase = s*16384 + h*512 + (l&31)*16 bytes,
// per-i4 address = (vbase ^ (i4<<4)) + (i4<<10)  (bit-disjoint, no carries).
__device__ __forceinline__ float4 lds_read(const char* ldsB, int vbase, int i4) {
  return *reinterpret_cast<const float4*>(ldsB + ((vbase ^ (i4 << 4)) + (i4 << 10)));
}

// Stage 4 windows: (s,h) -> cols [s*sS + h*hS + i0, +64) of 32 rows into the 2 buffers.
template<bool RELU, bool GATHER>
__device__ __forceinline__ void stage4(const float* __restrict__ src, int ldk,
                                       const int* __restrict__ tokL, int rbase,
                                       int sS, int hS, int i0,
                                       float4* __restrict__ lds4, int tid) {
  const int w = tid >> 7, t7 = tid & 127;
  const int row = t7 >> 2;
  const int s = w >> 1, h = w & 1;
  const int colbase = s * sS + h * hS + i0;
  const int r = GATHER ? tokL[row] : (rbase + row);
  const float* rp = src + (size_t)r * ldk + colbase;
#pragma unroll
  for (int u = 0; u < 4; ++u) {
    const int f4 = (t7 & 3) + 4 * u;
    float4 v = *reinterpret_cast<const float4*>(rp + f4 * 4);
    if (RELU) {
      v.x = fmaxf(v.x, 0.f); v.y = fmaxf(v.y, 0.f);
      v.z = fmaxf(v.z, 0.f); v.w = fmaxf(v.w, 0.f);
    }
    lds4[s * 1024 + f4 * 64 + h * 32 + (row ^ f4)] = v;
  }
}

__global__ __launch_bounds__(256) void k_init(const float* __restrict__ efs,
                                              float* __restrict__ h0, float* __restrict__ h1,
                                              u64* __restrict__ part) {
  int b = blockIdx.x, tid = threadIdx.x;
  for (int k = tid; k < HID_; k += 256) {
    h0[(size_t)b * HID_ + k] = efs[(size_t)b * HID_ + k];
    h1[(size_t)b * HID_ + k] = efs[(size_t)B_ * HID_ + (size_t)b * HID_ + k];
  }
  if (tid == 0) part[b] = (u64)(0xFFFFFFFFu - (u32)SOS_);
}

// Phase 1: WGs 0..255: GRU0 -> h0n ; WGs 256..511: gh1 = h1@Whh1^T + bhh1 -> gh1T
__global__ __launch_bounds__(512, 4) void k_p1(
    const u64* __restrict__ part, const float* __restrict__ embW,
    const float* __restrict__ h0, const float* __restrict__ h1,
    const float* __restrict__ Wih0, const float* __restrict__ Whh0,
    const float* __restrict__ bih0, const float* __restrict__ bhh0,
    const float* __restrict__ Whh1, const float* __restrict__ bhh1,
    float* __restrict__ h0n, float* __restrict__ gh1T) {
  __shared__ __align__(16) float4 lds4[2048];
  __shared__ float ldsP[8 * 12 * 32];
  __shared__ float ldsE[8 * 32];
  __shared__ int tokL[32];
  const char* ldsB = reinterpret_cast<const char*>(lds4);
  const int tid  = threadIdx.x;
  const int lane = tid & 63;
  const int bl   = lane & 31;
  const int h    = lane >> 5;
  const int wv   = __builtin_amdgcn_readfirstlane(tid >> 6);
  const int cg   = wv >> 1, s = wv & 1;
  const int wg   = blockIdx.x;
  const int bg   = wg & 1;
  const int vbase = s * 16384 + h * 512 + bl * 16;

  if (wg < 256) {
    const int colbase = (wg >> 1) * 8;
    const int c0 = __builtin_amdgcn_readfirstlane(colbase + cg * 2);
    if (tid < 32) tokL[tid] = (int)(0xFFFFFFFFu - (u32)(part[bg * 32 + tid] & 0xFFFFFFFFu));
    float acc[12];
#pragma unroll
    for (int j = 0; j < 12; ++j) acc[j] = 0.f;
    const float* wip[6]; const float* whp[6];
#pragma unroll
    for (int cc = 0; cc < 2; ++cc)
#pragma unroll
      for (int g = 0; g < 3; ++g) {
        wip[cc * 3 + g] = Wih0 + (size_t)(g * HID_ + c0 + cc) * EMB_;
        whp[cc * 3 + g] = Whh0 + (size_t)(g * HID_ + c0 + cc) * HID_;
      }
    const int klx = s * 256 + h * 128;
    const int klh = s * 512 + h * 256;
    for (int it = 0; it < 2; ++it) {            // gi over x = relu(emb[tok]), K=512
      __syncthreads();
      stage4<true, true>(embW, EMB_, tokL, 0, 256, 128, it * 64, lds4, tid);
      __syncthreads();
#pragma unroll 2
      for (int i4 = 0; i4 < 16; ++i4) {
        const float4 a = lds_read(ldsB, vbase, i4);
        const int kk = klx + it * 64 + i4 * 4;
#pragma unroll
        for (int j = 0; j < 6; ++j) {
          const float4 w4 = *reinterpret_cast<const float4*>(wip[j] + kk);
          acc[j] = fmaf(a.x, w4.x, acc[j]);
          acc[j] = fmaf(a.y, w4.y, acc[j]);
          acc[j] = fmaf(a.z, w4.z, acc[j]);
          acc[j] = fmaf(a.w, w4.w, acc[j]);
        }
      }
    }
    for (int it = 0; it < 4; ++it) {            // gh over h0, K=1024
      __syncthreads();
      stage4<false, false>(h0, HID_, nullptr, bg * 32, 512, 256, it * 64, lds4, tid);
      __syncthreads();
#pragma unroll 2
      for (int i4 = 0; i4 < 16; ++i4) {
        const float4 a = lds_read(ldsB, vbase, i4);
        const int kk = klh + it * 64 + i4 * 4;
#pragma unroll
        for (int j = 0; j < 6; ++j) {
          const float4 w4 = *reinterpret_cast<const float4*>(whp[j] + kk);
          acc[6 + j] = fmaf(a.x, w4.x, acc[6 + j]);
          acc[6 + j] = fmaf(a.y, w4.y, acc[6 + j]);
          acc[6 + j] = fmaf(a.z, w4.z, acc[6 + j]);
          acc[6 + j] = fmaf(a.w, w4.w, acc[6 + j]);
        }
      }
    }
#pragma unroll
    for (int j = 0; j < 12; ++j) acc[j] += __shfl_xor(acc[j], 32, 64);
    __syncthreads();
    if (lane < 32) {
#pragma unroll
      for (int j = 0; j < 12; ++j) ldsP[(wv * 12 + j) * 32 + bl] = acc[j];
    }
    __syncthreads();
    if (s == 0 && lane < 32) {
      const int p0 = (cg * 2) * 12, p1 = (cg * 2 + 1) * 12;
#pragma unroll
      for (int cc = 0; cc < 2; ++cc) {
        const int c = c0 + cc;
        const float gir = ldsP[(p0 + cc * 3 + 0) * 32 + bl] + ldsP[(p1 + cc * 3 + 0) * 32 + bl];
        const float giz = ldsP[(p0 + cc * 3 + 1) * 32 + bl] + ldsP[(p1 + cc * 3 + 1) * 32 + bl];
        const float gin = ldsP[(p0 + cc * 3 + 2) * 32 + bl] + ldsP[(p1 + cc * 3 + 2) * 32 + bl];
        const float ghr = ldsP[(p0 + 6 + cc * 3 + 0) * 32 + bl] + ldsP[(p1 + 6 + cc * 3 + 0) * 32 + bl];
        const float ghz = ldsP[(p0 + 6 + cc * 3 + 1) * 32 + bl] + ldsP[(p1 + 6 + cc * 3 + 1) * 32 + bl];
        const float ghn = ldsP[(p0 + 6 + cc * 3 + 2) * 32 + bl] + ldsP[(p1 + 6 + cc * 3 + 2) * 32 + bl];
        const float ir = gir + bih0[c], iz = giz + bih0[HID_ + c], in_ = gin + bih0[2 * HID_ + c];
        const float hr = ghr + bhh0[c], hz = ghz + bhh0[HID_ + c], hn = ghn + bhh0[2 * HID_ + c];
        const float r = sig_(ir + hr), z = sig_(iz + hz);
        const float n = tanhf(in_ + r * hn);
        const float hv = h0[(size_t)(bg * 32 + bl) * HID_ + c];
        ldsE[(cg * 2 + cc) * 32 + bl] = (1.f - z) * n + z * hv;
      }
    }
    __syncthreads();
    if (tid < 256) {
      const int b = tid >> 3, c = tid & 7;
      h0n[(size_t)(bg * 32 + b) * HID_ + colbase + c] = ldsE[c * 32 + b];
    }
  } else {
    const int colbase = ((wg - 256) >> 1) * 8;
    const int c0 = __builtin_amdgcn_readfirstlane(colbase + cg * 2);
    float acc[6];
#pragma unroll
    for (int j = 0; j < 6; ++j) acc[j] = 0.f;
    const float* whp[6];
#pragma unroll
    for (int cc = 0; cc < 2; ++cc)
#pragma unroll
      for (int g = 0; g < 3; ++g)
        whp[cc * 3 + g] = Whh1 + (size_t)(g * HID_ + c0 + cc) * HID_;
    const int klh = s * 512 + h * 256;
    for (int it = 0; it < 4; ++it) {
      __syncthreads();
      stage4<false, false>(h1, HID_, nullptr, bg * 32, 512, 256, it * 64, lds4, tid);
      __syncthreads();
#pragma unroll 2
      for (int i4 = 0; i4 < 16; ++i4) {
        const float4 a = lds_read(ldsB, vbase, i4);
        const int kk = klh + it * 64 + i4 * 4;
#pragma unroll
        for (int j = 0; j < 6; ++j) {
          const float4 w4 = *reinterpret_cast<const float4*>(whp[j] + kk);
          acc[j] = fmaf(a.x, w4.x, acc[j]);
          acc[j] = fmaf(a.y, w4.y, acc[j]);
          acc[j] = fmaf(a.z, w4.z, acc[j]);
          acc[j] = fmaf(a.w, w4.w, acc[j]);
        }
      }
    }
#pragma unroll
    for (int j = 0; j < 6; ++j) acc[j] += __shfl_xor(acc[j], 32, 64);
    __syncthreads();
    if (lane < 32) {
#pragma unroll
      for (int j = 0; j < 6; ++j) ldsP[(wv * 6 + j) * 32 + bl] = acc[j];
    }
    __syncthreads();
    if (s == 0 && lane < 32) {
      const int p0 = (cg * 2) * 6, p1 = (cg * 2 + 1) * 6;
#pragma unroll
      for (int cc = 0; cc < 2; ++cc)
#pragma unroll
        for (int g = 0; g < 3; ++g) {
          const int c = c0 + cc;
          const float v = ldsP[(p0 + cc * 3 + g) * 32 + bl] + ldsP[(p1 + cc * 3 + g) * 32 + bl]
                        + bhh1[g * HID_ + c];
          gh1T[(size_t)(g * HID_ + c) * 64 + bg * 32 + bl] = v;
        }
    }
  }
}

// Phase 2: gi1 = h0n@Wih1^T ; combine with gh1T -> h1n
__global__ __launch_bounds__(512, 4) void k_p2(
    const float* __restrict__ h0n, const float* __restrict__ gh1T, const float* __restrict__ h1,
    const float* __restrict__ Wih1, const float* __restrict__ bih1, float* __restrict__ h1n) {
  __shared__ __align__(16) float4 lds4[2048];
  __shared__ float ldsP[8 * 6 * 32];
  __shared__ float ldsE[8 * 32];
  const char* ldsB = reinterpret_cast<const char*>(lds4);
  const int tid = threadIdx.x, lane = tid & 63, bl = lane & 31, h = lane >> 5;
  const int wv = __builtin_amdgcn_readfirstlane(tid >> 6);
  const int cg = wv >> 1, s = wv & 1;
  const int wg = blockIdx.x, bg = wg & 1;
  const int colbase = (wg >> 1) * 8;
  const int c0 = __builtin_amdgcn_readfirstlane(colbase + cg * 2);
  const int vbase = s * 16384 + h * 512 + bl * 16;
  float acc[6];
#pragma unroll
  for (int j = 0; j < 6; ++j) acc[j] = 0.f;
  const float* wip[6];
#pragma unroll
  for (int cc = 0; cc < 2; ++cc)
#pragma unroll
    for (int g = 0; g < 3; ++g)
      wip[cc * 3 + g] = Wih1 + (size_t)(g * HID_ + c0 + cc) * HID_;
  const int klh = s * 512 + h * 256;
  for (int it = 0; it < 4; ++it) {
    __syncthreads();
    stage4<false, false>(h0n, HID_, nullptr, bg * 32, 512, 256, it * 64, lds4, tid);
    __syncthreads();
#pragma unroll 2
    for (int i4 = 0; i4 < 16; ++i4) {
      const float4 a = lds_read(ldsB, vbase, i4);
      const int kk = klh + it * 64 + i4 * 4;
#pragma unroll
      for (int j = 0; j < 6; ++j) {
        const float4 w4 = *reinterpret_cast<const float4*>(wip[j] + kk);
        acc[j] = fmaf(a.x, w4.x, acc[j]);
        acc[j] = fmaf(a.y, w4.y, acc[j]);
        acc[j] = fmaf(a.z, w4.z, acc[j]);
        acc[j] = fmaf(a.w, w4.w, acc[j]);
      }
    }
  }
#pragma unroll
  for (int j = 0; j < 6; ++j) acc[j] += __shfl_xor(acc[j], 32, 64);
  __syncthreads();
  if (lane < 32) {
#pragma unroll
    for (int j = 0; j < 6; ++j) ldsP[(wv * 6 + j) * 32 + bl] = acc[j];
  }
  __syncthreads();
  if (s == 0 && lane < 32) {
    const int p0 = (cg * 2) * 6, p1 = (cg * 2 + 1) * 6;
#pragma unroll
    for (int cc = 0; cc < 2; ++cc) {
      const int c = c0 + cc;
      const float gir = ldsP[(p0 + cc * 3 + 0) * 32 + bl] + ldsP[(p1 + cc * 3 + 0) * 32 + bl];
      const float giz = ldsP[(p0 + cc * 3 + 1) * 32 + bl] + ldsP[(p1 + cc * 3 + 1) * 32 + bl];
      const float gin = ldsP[(p0 + cc * 3 + 2) * 32 + bl] + ldsP[(p1 + cc * 3 + 2) * 32 + bl];
      const float ir = gir + bih1[c], iz = giz + bih1[HID_ + c], in_ = gin + bih1[2 * HID_ + c];
      const float hr = gh1T[(size_t)(0 * HID_ + c) * 64 + bg * 32 + bl];
      const float hz = gh1T[(size_t)(1 * HID_ + c) * 64 + bg * 32 + bl];
      const float hn = gh1T[(size_t)(2 * HID_ + c) * 64 + bg * 32 + bl];
      const float r = sig_(ir + hr), z = sig_(iz + hz);
      const float n = tanhf(in_ + r * hn);
      const float hv = h1[(size_t)(bg * 32 + bl) * HID_ + c];
      ldsE[(cg * 2 + cc) * 32 + bl] = (1.f - z) * n + z * hv;
    }
  }
  __syncthreads();
  if (tid < 256) {
    const int b = tid >> 3, c = tid & 7;
    h1n[(size_t)(bg * 32 + b) * HID_ + colbase + c] = ldsE[c * 32 + b];
  }
}

// Phase 3: hid = relu(h1n @ pW1^T + pb1); also resets argmax accumulator
__global__ __launch_bounds__(512, 4) void k_p3(
    const float* __restrict__ h1n, const float* __restrict__ pW1,
    const float* __restrict__ pb1, float* __restrict__ hid, u64* __restrict__ part) {
  __shared__ __align__(16) float4 lds4[2048];
  __shared__ float ldsP[8 * 4 * 32];
  __shared__ float ldsE[16 * 32];
  const char* ldsB = reinterpret_cast<const char*>(lds4);
  const int tid = threadIdx.x, lane = tid & 63, bl = lane & 31, h = lane >> 5;
  const int wv = __builtin_amdgcn_readfirstlane(tid >> 6);
  const int cg = wv >> 1, s = wv & 1;
  const int wg = blockIdx.x, bg = wg & 1;
  const int colbase = (wg >> 1) * 16;
  const int c0 = __builtin_amdgcn_readfirstlane(colbase + cg * 4);
  const int vbase = s * 16384 + h * 512 + bl * 16;
  if (wg == 0 && tid < 64) part[tid] = 0ull;
  float acc[4];
#pragma unroll
  for (int j = 0; j < 4; ++j) acc[j] = 0.f;
  const float* wp[4];
#pragma unroll
  for (int j = 0; j < 4; ++j) wp[j] = pW1 + (size_t)(c0 + j) * HID_;
  const int klh = s * 512 + h * 256;
  for (int it = 0; it < 4; ++it) {
    __syncthreads();
    stage4<false, false>(h1n, HID_, nullptr, bg * 32, 512, 256, it * 64, lds4, tid);
    __syncthreads();
#pragma unroll 2
    for (int i4 = 0; i4 < 16; ++i4) {
      const float4 a = lds_read(ldsB, vbase, i4);
      const int kk = klh + it * 64 + i4 * 4;
#pragma unroll
      for (int j = 0; j < 4; ++j) {
        const float4 w4 = *reinterpret_cast<const float4*>(wp[j] + kk);
        acc[j] = fmaf(a.x, w4.x, acc[j]);
        acc[j] = fmaf(a.y, w4.y, acc[j]);
        acc[j] = fmaf(a.z, w4.z, acc[j]);
        acc[j] = fmaf(a.w, w4.w, acc[j]);
      }
    }
  }
#pragma unroll
  for (int j = 0; j < 4; ++j) acc[j] += __shfl_xor(acc[j], 32, 64);
  __syncthreads();
  if (lane < 32) {
#pragma unroll
    for (int j = 0; j < 4; ++j) ldsP[(wv * 4 + j) * 32 + bl] = acc[j];
  }
  __syncthreads();
  if (s == 0 && lane < 32) {
    const int p0 = (cg * 2) * 4, p1 = (cg * 2 + 1) * 4;
#pragma unroll
    for (int j = 0; j < 4; ++j) {
      const float v = ldsP[(p0 + j) * 32 + bl] + ldsP[(p1 + j) * 32 + bl] + pb1[c0 + j];
      ldsE[(cg * 4 + j) * 32 + bl] = fmaxf(v, 0.f);
    }
  }
  __syncthreads();
  {
    const int b = tid >> 4, c = tid & 15;
    hid[(size_t)(bg * 32 + b) * HID_ + colbase + c] = ldsE[c * 32 + b];
  }
}

// Phase 4: logits (40 cols/WG) + coalesced store + argmax partial via packed atomicMax
__global__ __launch_bounds__(512, 4) void k_p4(
    const float* __restrict__ hid, const float* __restrict__ pW2,
    const float* __restrict__ pb2, float* __restrict__ out,
    u64* __restrict__ part, int t) {
  __shared__ __align__(16) float4 lds4[2048];
  __shared__ float ldsP[8 * 10 * 32];
  __shared__ float ldsO[40 * 32];
  const char* ldsB = reinterpret_cast<const char*>(lds4);
  const int tid = threadIdx.x, lane = tid & 63, bl = lane & 31, h = lane >> 5;
  const int wv = __builtin_amdgcn_readfirstlane(tid >> 6);
  const int cg = wv >> 1, s = wv & 1;
  const int wg = blockIdx.x, bg = wg & 1;
  const int colbase = (wg >> 1) * 40;
  const int c0 = __builtin_amdgcn_readfirstlane(colbase + cg * 10);
  const int vbase = s * 16384 + h * 512 + bl * 16;
  float acc[10];
#pragma unroll
  for (int j = 0; j < 10; ++j) acc[j] = 0.f;
  const float* wp[10];
#pragma unroll
  for (int j = 0; j < 10; ++j) wp[j] = pW2 + (size_t)(c0 + j) * HID_;
  const int klh = s * 512 + h * 256;
  for (int it = 0; it < 4; ++it) {
    __syncthreads();
    stage4<false, false>(hid, HID_, nullptr, bg * 32, 512, 256, it * 64, lds4, tid);
    __syncthreads();
#pragma unroll 2
    for (int i4 = 0; i4 < 16; ++i4) {
      const float4 a = lds_read(ldsB, vbase, i4);
      const int kk = klh + it * 64 + i4 * 4;
#pragma unroll
      for (int j = 0; j < 10; ++j) {
        const float4 w4 = *reinterpret_cast<const float4*>(wp[j] + kk);
        acc[j] = fmaf(a.x, w4.x, acc[j]);
        acc[j] = fmaf(a.y, w4.y, acc[j]);
        acc[j] = fmaf(a.z, w4.z, acc[j]);
        acc[j] = fmaf(a.w, w4.w, acc[j]);
      }
    }
  }
#pragma unroll
  for (int j = 0; j < 10; ++j) acc[j] += __shfl_xor(acc[j], 32, 64);
  __syncthreads();
  if (lane < 32) {
#pragma unroll
    for (int j = 0; j < 10; ++j) ldsP[(wv * 10 + j) * 32 + bl] = acc[j];
  }
  __syncthreads();
  if (s == 0 && lane < 32) {
    const int p0 = (cg * 2) * 10, p1 = (cg * 2 + 1) * 10;
#pragma unroll
    for (int j = 0; j < 10; ++j) {
      const float v = ldsP[(p0 + j) * 32 + bl] + ldsP[(p1 + j) * 32 + bl] + pb2[c0 + j];
      ldsO[(cg * 10 + j) * 32 + bl] = v;
    }
  }
  __syncthreads();
  {
    const int b = tid >> 4;
#pragma unroll
    for (int cc = 0; cc < 48; cc += 16) {
      const int c = cc + (tid & 15);
      if (c < 40)
        out[((size_t)(bg * 32 + b) * T_ + t) * V_ + colbase + c] = ldsO[c * 32 + b];
    }
  }
  if (tid < 32) {
    float best = -3.4e38f;
    int bi = 0;
    for (int c = 0; c < 40; ++c) {
      const float v = ldsO[c * 32 + tid];
      if (v > best) { best = v; bi = c; }
    }
    u32 kb = __float_as_uint(best);
    kb = (kb & 0x80000000u) ? ~kb : (kb | 0x80000000u);
    const u64 pk = ((u64)kb << 32) | (u64)(0xFFFFFFFFu - (u32)(colbase + bi));
    atomicMax(&part[bg * 32 + tid], pk);
  }
}

extern "C" void kernel_launch(void* const* d_in, const int* in_sizes, int n_in,
                              void* d_out, int out_size, void* d_ws, size_t ws_size,
                              hipStream_t stream) {
  (void)in_sizes; (void)n_in; (void)out_size; (void)ws_size;
  const float* efs  = (const float*)d_in[1];
  const float* embW = (const float*)d_in[2];
  const float* Wih0 = (const float*)d_in[3];
  const float* Whh0 = (const float*)d_in[4];
  const float* bih0 = (const float*)d_in[5];
  const float* bhh0 = (const float*)d_in[6];
  const float* Wih1 = (const float*)d_in[7];
  const float* Whh1 = (const float*)d_in[8];
  const float* bih1 = (const float*)d_in[9];
  const float* bhh1 = (const float*)d_in[10];
  const float* pW1  = (const float*)d_in[11];
  const float* pb1  = (const float*)d_in[12];
  const float* pW2  = (const float*)d_in[13];
  const float* pb2  = (const float*)d_in[14];
  float* out = (float*)d_out;

  float* ws   = (float*)d_ws;
  float* h0a  = ws;
  float* h0b  = h0a + 65536;
  float* h1a  = h0b + 65536;
  float* h1b  = h1a + 65536;
  float* gh1T = h1b + 65536;         // 3*1024*64
  float* hid  = gh1T + 196608;       // 64*1024
  u64*   part = (u64*)(hid + 65536); // 64

  k_init<<<dim3(B_), dim3(256), 0, stream>>>(efs, h0a, h1a, part);
  for (int t = 0; t < T_; ++t) {
    float* hc0 = (t & 1) ? h0b : h0a;
    float* hn0 = (t & 1) ? h0a : h0b;
    float* hc1 = (t & 1) ? h1b : h1a;
    float* hn1 = (t & 1) ? h1a : h1b;
    k_p1<<<dim3(512), dim3(512), 0, stream>>>(part, embW, hc0, hc1, Wih0, Whh0,
                                              bih0, bhh0, Whh1, bhh1, hn0, gh1T);
    k_p2<<<dim3(256), dim3(512), 0, stream>>>(hn0, gh1T, hc1, Wih1, bih1, hn1);
    k_p3<<<dim3(128), dim3(512), 0, stream>>>(hn1, pW1, pb1, hid, part);
    k_p4<<<dim3(500), dim3(512), 0, stream>>>(hid, pW2, pb2, out, part, t);
  }
}

// Round 4
// 30056.769 us; speedup vs baseline: 2.9035x; 1.6443x over previous
//
#include <hip/hip_runtime.h>
#include <stdint.h>

#define B_    64
#define EMB_  512
#define HID_  1024
#define V_    10000
#define T_    256
#define SOS_  1

typedef unsigned long long u64;
typedef unsigned int u32;

__device__ __forceinline__ float sig_(float v) { return 1.0f / (1.0f + __expf(-v)); }

// partial-buffer addressing: GEMM WGs store per-lane 4x4 patches as 4 coalesced
// float4 rows; poff maps (j-in-tile, b) -> float offset within a 4096-float slot.
__device__ __forceinline__ int poff(int j6, int b) {
  const int wv = j6 >> 4, r = j6 & 15;
  const int tidp = wv * 64 + (r >> 2) * 16 + (b >> 2);
  return ((b & 3) * 256 + tidp) * 4 + (r & 3);
}

// ---- GEMM building blocks ------------------------------------------------
// LDS: ldsA[128][64] = A^T chunk (k-major), ldsW[128][64] = W^T chunk.
__device__ __forceinline__ void gemm_chunk(const float* __restrict__ ldsA,
                                           const float* __restrict__ ldsW,
                                           int aoff, int woff, float acc[4][4]) {
#pragma unroll 4
  for (int k = 0; k < 128; ++k) {
    const float4 a = *reinterpret_cast<const float4*>(ldsA + k * 64 + aoff);
    const float4 w = *reinterpret_cast<const float4*>(ldsW + k * 64 + woff);
    acc[0][0] = fmaf(a.x, w.x, acc[0][0]); acc[0][1] = fmaf(a.x, w.y, acc[0][1]);
    acc[0][2] = fmaf(a.x, w.z, acc[0][2]); acc[0][3] = fmaf(a.x, w.w, acc[0][3]);
    acc[1][0] = fmaf(a.y, w.x, acc[1][0]); acc[1][1] = fmaf(a.y, w.y, acc[1][1]);
    acc[1][2] = fmaf(a.y, w.z, acc[1][2]); acc[1][3] = fmaf(a.y, w.w, acc[1][3]);
    acc[2][0] = fmaf(a.z, w.x, acc[2][0]); acc[2][1] = fmaf(a.z, w.y, acc[2][1]);
    acc[2][2] = fmaf(a.z, w.z, acc[2][2]); acc[2][3] = fmaf(a.z, w.w, acc[2][3]);
    acc[3][0] = fmaf(a.w, w.x, acc[3][0]); acc[3][1] = fmaf(a.w, w.y, acc[3][1]);
    acc[3][2] = fmaf(a.w, w.z, acc[3][2]); acc[3][3] = fmaf(a.w, w.w, acc[3][3]);
  }
}

__device__ __forceinline__ void stage_w(const float* __restrict__ W, int ldk,
                                        int jbase, int kofs, int Nw,
                                        float* __restrict__ ldsW, int tid) {
  const int jj = tid & 63;
  int j = jbase + jj; if (j > Nw - 1) j = Nw - 1;
  const int seg = tid >> 6;
  const float* src = W + (size_t)j * ldk + kofs + seg * 32;
#pragma unroll
  for (int u = 0; u < 8; ++u) {
    const float4 v = *reinterpret_cast<const float4*>(src + u * 4);
    const int k = seg * 32 + u * 4;
    ldsW[(k + 0) * 64 + jj] = v.x;
    ldsW[(k + 1) * 64 + jj] = v.y;
    ldsW[(k + 2) * 64 + jj] = v.z;
    ldsW[(k + 3) * 64 + jj] = v.w;
  }
}

__device__ __forceinline__ void stage_a_lin(const float* __restrict__ At, int kbase,
                                            float* __restrict__ ldsA, int tid) {
  const float4* src = reinterpret_cast<const float4*>(At + (size_t)kbase * 64);
  float4* dst = reinterpret_cast<float4*>(ldsA);
#pragma unroll
  for (int c = 0; c < 8; ++c) dst[c * 256 + tid] = src[c * 256 + tid];
}

__device__ __forceinline__ void stage_a_emb(const float* __restrict__ emb, int tok,
                                            int kofs, float* __restrict__ ldsA, int tid) {
  const int b = tid & 63, seg = tid >> 6;
  const float* src = emb + (size_t)tok * EMB_ + kofs + seg * 32;
#pragma unroll
  for (int u = 0; u < 8; ++u) {
    float4 v = *reinterpret_cast<const float4*>(src + u * 4);
    v.x = fmaxf(v.x, 0.f); v.y = fmaxf(v.y, 0.f);
    v.z = fmaxf(v.z, 0.f); v.w = fmaxf(v.w, 0.f);
    const int k = seg * 32 + u * 4;
    ldsA[(k + 0) * 64 + b] = v.x;
    ldsA[(k + 1) * 64 + b] = v.y;
    ldsA[(k + 2) * 64 + b] = v.z;
    ldsA[(k + 3) * 64 + b] = v.w;
  }
}

__device__ __forceinline__ void store_part(float* __restrict__ part, int slot,
                                           int tid, const float acc[4][4]) {
  float4* p4 = reinterpret_cast<float4*>(part + (size_t)slot * 4096);
#pragma unroll
  for (int ai = 0; ai < 4; ++ai)
    p4[ai * 256 + tid] = make_float4(acc[ai][0], acc[ai][1], acc[ai][2], acc[ai][3]);
}

// ---- kernels -------------------------------------------------------------

__global__ __launch_bounds__(256) void k_init(const float* __restrict__ efs,
                                              float* __restrict__ h0T,
                                              float* __restrict__ h1T,
                                              u64* __restrict__ part) {
  const int idx = blockIdx.x * 256 + threadIdx.x;   // grid 256 -> 65536
  const int k = idx >> 6, b = idx & 63;
  h0T[idx] = efs[(size_t)b * HID_ + k];
  h1T[idx] = efs[(size_t)B_ * HID_ + (size_t)b * HID_ + k];
  if (idx < 64) part[idx] = (u64)(0xFFFFFFFFu - (u32)SOS_);
}

// P1: wg<288: G0 = [x|h0] @ [Wih0;Whh0]^T (N=3072, K=1536, S=6)
//     wg>=288: G1h = h1 @ Whh1^T          (N=3072, K=1024, S=4)
__global__ __launch_bounds__(256, 2) void k_p1(
    const u64* __restrict__ part, const float* __restrict__ emb,
    const float* __restrict__ h0T, const float* __restrict__ h1T,
    const float* __restrict__ Wih0, const float* __restrict__ Whh0,
    const float* __restrict__ Whh1,
    float* __restrict__ pG0, float* __restrict__ pG1h) {
  __shared__ float ldsA[128 * 64];
  __shared__ float ldsW[128 * 64];
  const int tid = threadIdx.x, wg = blockIdx.x;
  const int lane = tid & 63, wv = tid >> 6;
  const int bg = lane & 15, jg = lane >> 4;
  const int aoff = bg * 4, woff = wv * 16 + jg * 4;
  float acc[4][4];
#pragma unroll
  for (int i = 0; i < 4; ++i)
#pragma unroll
    for (int j = 0; j < 4; ++j) acc[i][j] = 0.f;

  if (wg < 288) {
    const int s = wg / 48, jt = wg % 48;
    const int jbase = jt * 64;
    int tok = 0;
    if (s < 2) tok = (int)(0xFFFFFFFFu - (u32)(part[tid & 63] & 0xFFFFFFFFu));
    for (int ch = 0; ch < 2; ++ch) {
      const int kbase = s * 256 + ch * 128;
      if (kbase < EMB_) {
        stage_a_emb(emb, tok, kbase, ldsA, tid);
        stage_w(Wih0, EMB_, jbase, kbase, 3072, ldsW, tid);
      } else {
        stage_a_lin(h0T, kbase - EMB_, ldsA, tid);
        stage_w(Whh0, HID_, jbase, kbase - EMB_, 3072, ldsW, tid);
      }
      __syncthreads();
      gemm_chunk(ldsA, ldsW, aoff, woff, acc);
      __syncthreads();
    }
    store_part(pG0, wg, tid, acc);
  } else {
    const int w2 = wg - 288;
    const int s = w2 / 48, jt = w2 % 48;
    const int jbase = jt * 64;
    for (int ch = 0; ch < 2; ++ch) {
      const int kbase = s * 256 + ch * 128;
      stage_a_lin(h1T, kbase, ldsA, tid);
      stage_w(Whh1, HID_, jbase, kbase, 3072, ldsW, tid);
      __syncthreads();
      gemm_chunk(ldsA, ldsW, aoff, woff, acc);
      __syncthreads();
    }
    store_part(pG1h, w2, tid, acc);
  }
}

// generic: part[wg] = A^T-tile @ W-tile, wg = s*NJT + jt, K-slice s of CHUNKS*128
__global__ __launch_bounds__(256, 2) void k_gemm(
    const float* __restrict__ At, const float* __restrict__ W,
    float* __restrict__ part, int ldk, int NJT, int CHUNKS, int Nw) {
  __shared__ float ldsA[128 * 64];
  __shared__ float ldsW[128 * 64];
  const int tid = threadIdx.x, wg = blockIdx.x;
  const int s = wg / NJT, jt = wg % NJT;
  const int jbase = jt * 64;
  const int lane = tid & 63, wv = tid >> 6;
  const int bg = lane & 15, jg = lane >> 4;
  const int aoff = bg * 4, woff = wv * 16 + jg * 4;
  float acc[4][4];
#pragma unroll
  for (int i = 0; i < 4; ++i)
#pragma unroll
    for (int j = 0; j < 4; ++j) acc[i][j] = 0.f;
  for (int ch = 0; ch < CHUNKS; ++ch) {
    const int kbase = s * (CHUNKS * 128) + ch * 128;
    stage_a_lin(At, kbase, ldsA, tid);
    stage_w(W, ldk, jbase, kbase, Nw, ldsW, tid);
    __syncthreads();
    gemm_chunk(ldsA, ldsW, aoff, woff, acc);
    __syncthreads();
  }
  store_part(part, wg, tid, acc);
}

// E1: GRU0 combine -> h0nT; resets argmax accumulator
__global__ __launch_bounds__(256) void k_e1(
    const float* __restrict__ pG0, const float* __restrict__ h0T,
    const float* __restrict__ bih0, const float* __restrict__ bhh0,
    float* __restrict__ h0nT, u64* __restrict__ part) {
  const int tid = threadIdx.x, wg = blockIdx.x;
  if (wg == 0 && tid < 64) part[tid] = 0ull;
  const int c = wg * 4 + (tid >> 6);
  const int b = tid & 63;
  float gi[3], gh[3];
#pragma unroll
  for (int g = 0; g < 3; ++g) {
    const int j = g * HID_ + c;
    const int jt = j >> 6, j6 = j & 63;
    const int o = poff(j6, b);
    gi[g] = pG0[(size_t)(0 * 48 + jt) * 4096 + o] + pG0[(size_t)(1 * 48 + jt) * 4096 + o];
    gh[g] = pG0[(size_t)(2 * 48 + jt) * 4096 + o] + pG0[(size_t)(3 * 48 + jt) * 4096 + o]
          + pG0[(size_t)(4 * 48 + jt) * 4096 + o] + pG0[(size_t)(5 * 48 + jt) * 4096 + o];
  }
  const float ir = gi[0] + bih0[c], iz = gi[1] + bih0[HID_ + c], in_ = gi[2] + bih0[2 * HID_ + c];
  const float hr = gh[0] + bhh0[c], hz = gh[1] + bhh0[HID_ + c], hn = gh[2] + bhh0[2 * HID_ + c];
  const float r = sig_(ir + hr), z = sig_(iz + hz);
  const float n = tanhf(in_ + r * hn);
  const float hv = h0T[c * 64 + b];
  h0nT[c * 64 + b] = (1.f - z) * n + z * hv;
}

// E2: GRU1 combine (gi from pG1i, gh from pG1h) -> h1nT
__global__ __launch_bounds__(256) void k_e2(
    const float* __restrict__ pG1i, const float* __restrict__ pG1h,
    const float* __restrict__ h1T,
    const float* __restrict__ bih1, const float* __restrict__ bhh1,
    float* __restrict__ h1nT) {
  const int tid = threadIdx.x, wg = blockIdx.x;
  const int c = wg * 4 + (tid >> 6);
  const int b = tid & 63;
  float gi[3], gh[3];
#pragma unroll
  for (int g = 0; g < 3; ++g) {
    const int j = g * HID_ + c;
    const int jt = j >> 6, j6 = j & 63;
    const int o = poff(j6, b);
    float si = 0.f, sh = 0.f;
#pragma unroll
    for (int s = 0; s < 4; ++s) {
      si += pG1i[(size_t)(s * 48 + jt) * 4096 + o];
      sh += pG1h[(size_t)(s * 48 + jt) * 4096 + o];
    }
    gi[g] = si; gh[g] = sh;
  }
  const float ir = gi[0] + bih1[c], iz = gi[1] + bih1[HID_ + c], in_ = gi[2] + bih1[2 * HID_ + c];
  const float hr = gh[0] + bhh1[c], hz = gh[1] + bhh1[HID_ + c], hn = gh[2] + bhh1[2 * HID_ + c];
  const float r = sig_(ir + hr), z = sig_(iz + hz);
  const float n = tanhf(in_ + r * hn);
  const float hv = h1T[c * 64 + b];
  h1nT[c * 64 + b] = (1.f - z) * n + z * hv;
}

// E3: hid = relu(FC1 partial-sum + pb1) -> hidT
__global__ __launch_bounds__(256) void k_e3(
    const float* __restrict__ pFC, const float* __restrict__ pb1,
    float* __restrict__ hidT) {
  const int tid = threadIdx.x, wg = blockIdx.x;
  const int c = wg * 4 + (tid >> 6);
  const int b = tid & 63;
  const int jt = c >> 6, j6 = c & 63;
  const int o = poff(j6, b);
  float s = pb1[c];
#pragma unroll
  for (int si = 0; si < 8; ++si) s += pFC[(size_t)(si * 16 + jt) * 4096 + o];
  hidT[c * 64 + b] = fmaxf(s, 0.f);
}

// E4: logits = V partial-sum + pb2; store out; wave argmax -> packed atomicMax
__global__ __launch_bounds__(256) void k_e4(
    const float* __restrict__ pV, const float* __restrict__ pb2,
    float* __restrict__ out, u64* __restrict__ part, int t) {
  const int tid = threadIdx.x, wg = blockIdx.x;
  const int jt = wg % 157, bq = wg / 157;
  const int lane = tid & 63, wv = tid >> 6;
  const int b = bq * 4 + wv;
  const int c = jt * 64 + lane;
  float v = -3.4e38f;
  if (c < V_) {
    float s = pb2[c];
    const int o = poff(lane, b);
#pragma unroll
    for (int si = 0; si < 4; ++si) s += pV[(size_t)(si * 157 + jt) * 4096 + o];
    out[((size_t)b * T_ + t) * V_ + c] = s;
    v = s;
  }
  u32 kb = __float_as_uint(v);
  kb = (kb & 0x80000000u) ? ~kb : (kb | 0x80000000u);
  u64 pk = ((u64)kb << 32) | (u64)(0xFFFFFFFFu - (u32)c);
#pragma unroll
  for (int d = 1; d < 64; d <<= 1) {
    const u64 o2 = __shfl_xor(pk, d, 64);
    if (o2 > pk) pk = o2;
  }
  if (lane == 0) atomicMax(&part[b], pk);
}

extern "C" void kernel_launch(void* const* d_in, const int* in_sizes, int n_in,
                              void* d_out, int out_size, void* d_ws, size_t ws_size,
                              hipStream_t stream) {
  (void)in_sizes; (void)n_in; (void)out_size; (void)ws_size;
  const float* efs  = (const float*)d_in[1];
  const float* embW = (const float*)d_in[2];
  const float* Wih0 = (const float*)d_in[3];
  const float* Whh0 = (const float*)d_in[4];
  const float* bih0 = (const float*)d_in[5];
  const float* bhh0 = (const float*)d_in[6];
  const float* Wih1 = (const float*)d_in[7];
  const float* Whh1 = (const float*)d_in[8];
  const float* bih1 = (const float*)d_in[9];
  const float* bhh1 = (const float*)d_in[10];
  const float* pW1  = (const float*)d_in[11];
  const float* pb1  = (const float*)d_in[12];
  const float* pW2  = (const float*)d_in[13];
  const float* pb2  = (const float*)d_in[14];
  float* out = (float*)d_out;

  float* ws   = (float*)d_ws;
  float* h0Ta = ws;                    // 65536
  float* h0Tb = ws + 65536;
  float* h1Ta = ws + 131072;
  float* h1Tb = ws + 196608;
  float* hidT = ws + 262144;
  float* pG0  = ws + 327680;           // 288*4096
  float* pG1h = ws + 1507328;          // 192*4096
  float* pG1i = ws + 2293760;          // 192*4096
  float* pFC  = ws + 3080192;          // 128*4096
  float* pV   = ws + 3604480;          // 628*4096
  u64*   part = (u64*)(ws + 6176768);  // 64 u64

  k_init<<<dim3(256), dim3(256), 0, stream>>>(efs, h0Ta, h1Ta, part);
  for (int t = 0; t < T_; ++t) {
    const float* h0c = (t & 1) ? h0Tb : h0Ta;
    float*       h0n = (t & 1) ? h0Ta : h0Tb;
    const float* h1c = (t & 1) ? h1Tb : h1Ta;
    float*       h1n = (t & 1) ? h1Ta : h1Tb;
    k_p1<<<dim3(480), dim3(256), 0, stream>>>(part, embW, h0c, h1c,
                                              Wih0, Whh0, Whh1, pG0, pG1h);
    k_e1<<<dim3(256), dim3(256), 0, stream>>>(pG0, h0c, bih0, bhh0, h0n, part);
    k_gemm<<<dim3(192), dim3(256), 0, stream>>>(h0n, Wih1, pG1i, HID_, 48, 2, 3072);
    k_e2<<<dim3(256), dim3(256), 0, stream>>>(pG1i, pG1h, h1c, bih1, bhh1, h1n);
    k_gemm<<<dim3(128), dim3(256), 0, stream>>>(h1n, pW1, pFC, HID_, 16, 1, HID_);
    k_e3<<<dim3(256), dim3(256), 0, stream>>>(pFC, pb1, hidT);
    k_gemm<<<dim3(628), dim3(256), 0, stream>>>(hidT, pW2, pV, HID_, 157, 2, V_);
    k_e4<<<dim3(2512), dim3(256), 0, stream>>>(pV, pb2, out, part, t);
  }
}